// Round 5
// baseline (152.437 us; speedup 1.0000x reference)
//
#include <hip/hip_runtime.h>
#include <hip/hip_bf16.h>
#include <math.h>

#define BATCH 16
#define SEQ   2048
#define HID   128
#define DIM   64

typedef __attribute__((ext_vector_type(8))) short bf16x8;
typedef __attribute__((ext_vector_type(4))) float f32x4;

// 0.125 (1/sqrt(D)) * log2(e): folded into Wq so MFMA emits log2-domain scores
#define QSCALE 0.18033688011112042f
#define C0_PE  0.07195578314043169f   // ln(10000)/128

static __device__ __forceinline__ ushort f2bf(float f) {
    union { float f; unsigned u; } v; v.f = f;
    unsigned r = v.u + 0x7FFFu + ((v.u >> 16) & 1u);   // RNE
    return (ushort)(r >> 16);
}

static __device__ __forceinline__ ushort2 pk_bf16(float a, float b) {
    union { __hip_bfloat162 h; ushort2 u; } v;
    v.h = __float22bfloat162_rn(make_float2(a, b));
    return v.u;
}

static __device__ __forceinline__ float fast_exp2(float x) {
#if __has_builtin(__builtin_amdgcn_exp2f)
    return __builtin_amdgcn_exp2f(x);
#else
    return exp2f(x);
#endif
}

// ---------------------------------------------------------------------------
// PE table: pet[pos][h], fp32, 2048 x 128 (1 MB)
// ---------------------------------------------------------------------------
__global__ __launch_bounds__(256) void k_pe(float* __restrict__ pet) {
    int i = blockIdx.x * 256 + threadIdx.x;      // pair index, 2048*64 total
    int pos = i >> 6, hp = i & 63;
    float ang = (float)pos * __expf(-(float)(2 * hp) * C0_PE);
    pet[pos * HID + 2 * hp]     = __sinf(ang);
    pet[pos * HID + 2 * hp + 1] = __cosf(ang);
}

// ---------------------------------------------------------------------------
// Prep: wvf[h] = Wv[h,:]·Wf  and  Wt[col][k] = bf16 of [Wq*QSCALE | Wk]^T
// ---------------------------------------------------------------------------
__global__ void k_prep(const float* __restrict__ Wq, const float* __restrict__ Wk,
                       const float* __restrict__ Wv, const float* __restrict__ Wf,
                       ushort* __restrict__ Wt, float* __restrict__ wvf) {
    const int tid = threadIdx.x;
    if (tid < HID) {
        float s = 0.f;
        #pragma unroll 8
        for (int d = 0; d < DIM; ++d) s += Wv[tid * DIM + d] * Wf[d];
        wvf[tid] = s;
    }
    for (int i = tid; i < 128 * 128; i += 256) {
        int col = i >> 7, k = i & 127;
        float v = (col < 64) ? Wq[k * DIM + col] * QSCALE : Wk[k * DIM + (col - 64)];
        Wt[i] = f2bf(v);
    }
}

// ---------------------------------------------------------------------------
// QKV (MFMA, no LDS): 512 threads = 8 waves; wave = (rowtile, colhalf).
// Each wave handles 16 rows and 4 of the 8 output col-tiles.
// A fragment = x + pet (table), packed with v_cvt_pk_bf16_f32.
// colhalf 0 -> Q tiles (prescaled), also computes vf; colhalf 1 -> K tiles.
// ---------------------------------------------------------------------------
__global__ __launch_bounds__(512) void k_qkv(
    const float* __restrict__ x, const float* __restrict__ pet,
    const ushort* __restrict__ Wt, const float* __restrict__ wvf,
    ushort* __restrict__ Qb, ushort* __restrict__ Kb, float* __restrict__ vf)
{
    const int tid  = threadIdx.x;
    const int wave = tid >> 6;
    const int lane = tid & 63;
    const int quad = lane >> 4;
    const int col  = lane & 15;
    const int rowtile  = blockIdx.x * 4 + (wave >> 1);
    const int colhalf  = wave & 1;
    const int rowbase  = rowtile * 16;
    const int grow = rowbase + col;              // this lane's xp row
    const int pos  = grow & (SEQ - 1);

    // ---- build A fragments (4 chunks of k=32) + vf partial ----
    bf16x8 af[4];
    float vpart = 0.f;
    #pragma unroll
    for (int c = 0; c < 4; ++c) {
        const float* xp = x   + (size_t)grow * HID + quad * 8 + c * 32;
        const float* pp = pet + (size_t)pos  * HID + quad * 8 + c * 32;
        float4 v0 = *(const float4*)(xp);
        float4 v1 = *(const float4*)(xp + 4);
        float4 p0 = *(const float4*)(pp);
        float4 p1 = *(const float4*)(pp + 4);
        float t[8] = {v0.x + p0.x, v0.y + p0.y, v0.z + p0.z, v0.w + p0.w,
                      v1.x + p1.x, v1.y + p1.y, v1.z + p1.z, v1.w + p1.w};
        if (colhalf == 0) {
            const float* wp = wvf + quad * 8 + c * 32;
            float4 w0 = *(const float4*)(wp);
            float4 w1 = *(const float4*)(wp + 4);
            vpart += t[0] * w0.x + t[1] * w0.y + t[2] * w0.z + t[3] * w0.w +
                     t[4] * w1.x + t[5] * w1.y + t[6] * w1.z + t[7] * w1.w;
        }
        ushort2* ap = (ushort2*)&af[c];
        #pragma unroll
        for (int j = 0; j < 4; ++j) ap[j] = pk_bf16(t[2 * j], t[2 * j + 1]);
    }

    if (colhalf == 0) {
        vpart += __shfl_xor(vpart, 16);
        vpart += __shfl_xor(vpart, 32);
        if (quad == 0) vf[grow] = vpart;
    }

    // ---- 4 col tiles for this half ----
    ushort* dst = colhalf ? Kb : Qb;
    #pragma unroll
    for (int t = 0; t < 4; ++t) {
        const ushort* wrow = Wt + (size_t)((colhalf * 4 + t) * 16 + col) * 128 + quad * 8;
        f32x4 acc = {0.f, 0.f, 0.f, 0.f};
        #pragma unroll
        for (int c = 0; c < 4; ++c) {
            bf16x8 bfr = *(const bf16x8*)(wrow + c * 32);
            acc = __builtin_amdgcn_mfma_f32_16x16x32_bf16(af[c], bfr, acc, 0, 0, 0);
        }
        // C layout: col = lane&15, row = quad*4 + r
        const int cb = t * 16 + col;
        const int r0 = rowbase + quad * 4;
        #pragma unroll
        for (int r = 0; r < 4; ++r)
            dst[(size_t)(r0 + r) * DIM + cb] = f2bf(acc[r]);
    }
}

// ---------------------------------------------------------------------------
// Stats (MFMA): block = (b, 64 k-cols), 8 waves sweep 256 q rows each,
// 32 rows per iteration (16 MFMA + 32 exp per iter for ILP).
// l[k] = sum_q exp2(s'[q,k]); wb = vf / l.
// ---------------------------------------------------------------------------
__global__ __launch_bounds__(512) void k_stats(
    const ushort* __restrict__ Qb, const ushort* __restrict__ Kb,
    const float* __restrict__ vf, float* __restrict__ wb)
{
    const int b    = blockIdx.y;
    const int k0   = blockIdx.x * 64;
    const int tid  = threadIdx.x;
    const int wave = tid >> 6;
    const int lane = tid & 63;
    const int quad = lane >> 4;
    const int col  = lane & 15;

    __shared__ float sl[8][64];

    bf16x8 kf[4][2];
    {
        const ushort* Kbase = Kb + ((size_t)(b * SEQ + k0)) * DIM;
        #pragma unroll
        for (int t = 0; t < 4; ++t)
            #pragma unroll
            for (int c = 0; c < 2; ++c)
                kf[t][c] = *(const bf16x8*)(Kbase + (size_t)(t * 16 + col) * DIM + quad * 8 + c * 32);
    }

    float l[4] = {0.f, 0.f, 0.f, 0.f};
    const ushort* Qrow = Qb + ((size_t)(b * SEQ + wave * 256 + col)) * DIM + quad * 8;

    for (int qi = 0; qi < 8; ++qi) {
        bf16x8 a00 = *(const bf16x8*)(Qrow);
        bf16x8 a01 = *(const bf16x8*)(Qrow + 32);
        bf16x8 a10 = *(const bf16x8*)(Qrow + 16 * DIM);
        bf16x8 a11 = *(const bf16x8*)(Qrow + 16 * DIM + 32);
        Qrow += 32 * DIM;
        #pragma unroll
        for (int t = 0; t < 4; ++t) {
            f32x4 acc0 = {0.f, 0.f, 0.f, 0.f};
            f32x4 acc1 = {0.f, 0.f, 0.f, 0.f};
            acc0 = __builtin_amdgcn_mfma_f32_16x16x32_bf16(a00, kf[t][0], acc0, 0, 0, 0);
            acc0 = __builtin_amdgcn_mfma_f32_16x16x32_bf16(a01, kf[t][1], acc0, 0, 0, 0);
            acc1 = __builtin_amdgcn_mfma_f32_16x16x32_bf16(a10, kf[t][0], acc1, 0, 0, 0);
            acc1 = __builtin_amdgcn_mfma_f32_16x16x32_bf16(a11, kf[t][1], acc1, 0, 0, 0);
            l[t] += fast_exp2(acc0.x) + fast_exp2(acc0.y) +
                    fast_exp2(acc0.z) + fast_exp2(acc0.w) +
                    fast_exp2(acc1.x) + fast_exp2(acc1.y) +
                    fast_exp2(acc1.z) + fast_exp2(acc1.w);
        }
    }

    #pragma unroll
    for (int t = 0; t < 4; ++t) {
        l[t] += __shfl_xor(l[t], 16);
        l[t] += __shfl_xor(l[t], 32);
    }
    if (quad == 0) {
        #pragma unroll
        for (int t = 0; t < 4; ++t) sl[wave][t * 16 + col] = l[t];
    }
    __syncthreads();

    if (tid < 64) {
        float ll = 0.f;
        #pragma unroll
        for (int w = 0; w < 8; ++w) ll += sl[w][tid];
        size_t g = (size_t)b * SEQ + k0 + tid;
        wb[g] = vf[g] / ll;
    }
}

// ---------------------------------------------------------------------------
// Out (MFMA): block = (b, 64 q-rows), 8 waves sweep 256 k cols each,
// 32 cols per iteration.  out[q] = bf + sum_k exp2(s'[q,k]) * w[k]
// ---------------------------------------------------------------------------
__global__ __launch_bounds__(512) void k_out(
    const ushort* __restrict__ Qb, const ushort* __restrict__ Kb,
    const float* __restrict__ wb, const float* __restrict__ bfp,
    float* __restrict__ outp)
{
    const int b    = blockIdx.y;
    const int q0   = blockIdx.x * 64;
    const int tid  = threadIdx.x;
    const int wave = tid >> 6;
    const int lane = tid & 63;
    const int quad = lane >> 4;
    const int col  = lane & 15;

    __shared__ float sred[8][64];

    bf16x8 qf[4][2];
    {
        const ushort* Qbase = Qb + ((size_t)(b * SEQ + q0)) * DIM;
        #pragma unroll
        for (int t = 0; t < 4; ++t)
            #pragma unroll
            for (int c = 0; c < 2; ++c)
                qf[t][c] = *(const bf16x8*)(Qbase + (size_t)(t * 16 + col) * DIM + quad * 8 + c * 32);
    }

    float rs[4][4] = {};
    const ushort* Krow = Kb + ((size_t)(b * SEQ + wave * 256 + col)) * DIM + quad * 8;
    const float*  wptr = wb + (size_t)b * SEQ + wave * 256 + col;

    for (int ki = 0; ki < 8; ++ki) {
        bf16x8 b00 = *(const bf16x8*)(Krow);
        bf16x8 b01 = *(const bf16x8*)(Krow + 32);
        bf16x8 b10 = *(const bf16x8*)(Krow + 16 * DIM);
        bf16x8 b11 = *(const bf16x8*)(Krow + 16 * DIM + 32);
        Krow += 32 * DIM;
        float wc0 = wptr[0];
        float wc1 = wptr[16];
        wptr += 32;
        #pragma unroll
        for (int t = 0; t < 4; ++t) {
            f32x4 acc0 = {0.f, 0.f, 0.f, 0.f};
            f32x4 acc1 = {0.f, 0.f, 0.f, 0.f};
            acc0 = __builtin_amdgcn_mfma_f32_16x16x32_bf16(qf[t][0], b00, acc0, 0, 0, 0);
            acc0 = __builtin_amdgcn_mfma_f32_16x16x32_bf16(qf[t][1], b01, acc0, 0, 0, 0);
            acc1 = __builtin_amdgcn_mfma_f32_16x16x32_bf16(qf[t][0], b10, acc1, 0, 0, 0);
            acc1 = __builtin_amdgcn_mfma_f32_16x16x32_bf16(qf[t][1], b11, acc1, 0, 0, 0);
            #pragma unroll
            for (int r = 0; r < 4; ++r)
                rs[t][r] += fast_exp2(acc0[r]) * wc0 + fast_exp2(acc1[r]) * wc1;
        }
    }

    // reduce over the 16 k-cols (low 4 lane bits)
    #pragma unroll
    for (int t = 0; t < 4; ++t)
        #pragma unroll
        for (int r = 0; r < 4; ++r) {
            float v = rs[t][r];
            v += __shfl_xor(v, 1); v += __shfl_xor(v, 2);
            v += __shfl_xor(v, 4); v += __shfl_xor(v, 8);
            rs[t][r] = v;
        }

    if (col == 0) {
        #pragma unroll
        for (int t = 0; t < 4; ++t)
            #pragma unroll
            for (int r = 0; r < 4; ++r)
                sred[wave][t * 16 + quad * 4 + r] = rs[t][r];
    }
    __syncthreads();

    if (tid < 64) {
        float s = bfp[0];
        #pragma unroll
        for (int w = 0; w < 8; ++w) s += sred[w][tid];
        outp[(size_t)b * SEQ + q0 + tid] = s;
    }
}

// ---------------------------------------------------------------------------
extern "C" void kernel_launch(void* const* d_in, const int* in_sizes, int n_in,
                              void* d_out, int out_size, void* d_ws, size_t ws_size,
                              hipStream_t stream) {
    (void)in_sizes; (void)n_in; (void)out_size; (void)ws_size;
    const float* x  = (const float*)d_in[0];
    const float* Wq = (const float*)d_in[1];
    const float* Wk = (const float*)d_in[2];
    const float* Wv = (const float*)d_in[3];
    const float* Wf = (const float*)d_in[4];
    const float* bf = (const float*)d_in[5];
    float* outp = (float*)d_out;

    float*  wvf = (float*)d_ws;                                  // 256 floats
    float*  vf  = wvf + 256;                                     // B*S
    float*  wb  = vf + (size_t)BATCH * SEQ;                      // B*S
    float*  pet = wb + (size_t)BATCH * SEQ;                      // SEQ*HID
    ushort* Wt  = (ushort*)(pet + (size_t)SEQ * HID);            // 128*128
    ushort* Qb  = Wt + 128 * 128;                                // B*S*D bf16
    ushort* Kb  = Qb + (size_t)BATCH * SEQ * DIM;                // B*S*D bf16

    k_pe<<<SEQ * (HID / 2) / 256, 256, 0, stream>>>(pet);
    k_prep<<<1, 256, 0, stream>>>(Wq, Wk, Wv, Wf, Wt, wvf);
    k_qkv<<<BATCH * SEQ / 64, 512, 0, stream>>>(x, pet, Wt, wvf, Qb, Kb, vf);
    k_stats<<<dim3(SEQ / 64, BATCH), 512, 0, stream>>>(Qb, Kb, vf, wb);
    k_out<<<dim3(SEQ / 64, BATCH), 512, 0, stream>>>(Qb, Kb, wb, bf, outp);
}

// Round 6
// 138.165 us; speedup vs baseline: 1.1033x; 1.1033x over previous
//
#include <hip/hip_runtime.h>
#include <hip/hip_bf16.h>
#include <math.h>

#define BATCH 16
#define SEQ   2048
#define HID   128
#define DIM   64

typedef __attribute__((ext_vector_type(8))) short bf16x8;
typedef __attribute__((ext_vector_type(4))) float f32x4;

// 0.125 (1/sqrt(D)) * log2(e): folded into Wq so MFMA emits log2-domain scores
#define QSCALE 0.18033688011112042f
#define C0_PE  0.07195578314043169f   // ln(10000)/128

static __device__ __forceinline__ ushort f2bf(float f) {
    union { float f; unsigned u; } v; v.f = f;
    unsigned r = v.u + 0x7FFFu + ((v.u >> 16) & 1u);   // RNE
    return (ushort)(r >> 16);
}

static __device__ __forceinline__ float fast_exp2(float x) {
#if __has_builtin(__builtin_amdgcn_exp2f)
    return __builtin_amdgcn_exp2f(x);
#else
    return exp2f(x);
#endif
}

// ---------------------------------------------------------------------------
// Prep: wvf[h] = Wv[h,:]·Wf  and  Wt[col][k] = bf16 of [Wq*QSCALE | Wk]^T
// ---------------------------------------------------------------------------
__global__ void k_prep(const float* __restrict__ Wq, const float* __restrict__ Wk,
                       const float* __restrict__ Wv, const float* __restrict__ Wf,
                       ushort* __restrict__ Wt, float* __restrict__ wvf) {
    const int tid = threadIdx.x;
    if (tid < HID) {
        float s = 0.f;
        #pragma unroll 8
        for (int d = 0; d < DIM; ++d) s += Wv[tid * DIM + d] * Wf[d];
        wvf[tid] = s;
    }
    for (int i = tid; i < 128 * 128; i += 256) {
        int col = i >> 7, k = i & 127;
        float v = (col < 64) ? Wq[k * DIM + col] * QSCALE : Wk[k * DIM + (col - 64)];
        Wt[i] = f2bf(v);
    }
}

// ---------------------------------------------------------------------------
// QKV (MFMA, no LDS): block = 64 rows, wave = 16 rows (R4-proven version).
// ---------------------------------------------------------------------------
__global__ __launch_bounds__(256) void k_qkv(
    const float* __restrict__ x, const ushort* __restrict__ Wt,
    const float* __restrict__ wvf, ushort* __restrict__ Qb,
    ushort* __restrict__ Kb, float* __restrict__ vf)
{
    const int tid  = threadIdx.x;
    const int wave = tid >> 6;
    const int lane = tid & 63;
    const int quad = lane >> 4;
    const int col  = lane & 15;
    const int rowbase = blockIdx.x * 64 + wave * 16;
    const int grow = rowbase + col;          // this lane's xp row (A m-index)
    const float pos = (float)(grow & (SEQ - 1));

    // ---- build A fragments (4 chunks of k=32) + vf partial ----
    bf16x8 af[4];
    float vpart = 0.f;
    #pragma unroll
    for (int c = 0; c < 4; ++c) {
        const float* xp = x + (size_t)grow * HID + quad * 8 + c * 32;
        float4 v0 = *(const float4*)(xp);
        float4 v1 = *(const float4*)(xp + 4);
        float t[8] = {v0.x, v0.y, v0.z, v0.w, v1.x, v1.y, v1.z, v1.w};
        #pragma unroll
        for (int jp = 0; jp < 4; ++jp) {
            int h = quad * 8 + c * 32 + jp * 2;      // even
            float ang = pos * __expf(-(float)h * C0_PE);
            t[jp * 2]     += __sinf(ang);
            t[jp * 2 + 1] += __cosf(ang);
        }
        const float* wp = wvf + quad * 8 + c * 32;
        float4 w0 = *(const float4*)(wp);
        float4 w1 = *(const float4*)(wp + 4);
        vpart += t[0] * w0.x + t[1] * w0.y + t[2] * w0.z + t[3] * w0.w +
                 t[4] * w1.x + t[5] * w1.y + t[6] * w1.z + t[7] * w1.w;
        short* ap = (short*)&af[c];
        #pragma unroll
        for (int j = 0; j < 8; ++j) ap[j] = (short)f2bf(t[j]);
    }

    vpart += __shfl_xor(vpart, 16);
    vpart += __shfl_xor(vpart, 32);
    if (quad == 0) vf[grow] = vpart;

    // ---- 8 col tiles: 0..3 -> Q (prescaled), 4..7 -> K ----
    #pragma unroll
    for (int t = 0; t < 8; ++t) {
        const ushort* wrow = Wt + (size_t)(t * 16 + col) * 128 + quad * 8;
        f32x4 acc = {0.f, 0.f, 0.f, 0.f};
        #pragma unroll
        for (int c = 0; c < 4; ++c) {
            bf16x8 bfr = *(const bf16x8*)(wrow + c * 32);
            acc = __builtin_amdgcn_mfma_f32_16x16x32_bf16(af[c], bfr, acc, 0, 0, 0);
        }
        // C layout: col = lane&15, row = quad*4 + r
        const int cb = (t & 3) * 16 + col;
        ushort* dst = (t < 4) ? Qb : Kb;
        const int r0 = rowbase + quad * 4;
        #pragma unroll
        for (int r = 0; r < 4; ++r)
            dst[(size_t)(r0 + r) * DIM + cb] = f2bf(acc[r]);
    }
}

// ---------------------------------------------------------------------------
// Fused attention (MFMA): block = (b, 64 k-cols), 512 threads = 8 waves.
// Phase A: waves jointly sweep all 2048 q rows -> full column sums l for
//          this block's 64 columns -> wcol = vf/l in LDS (block-local!).
// Phase B: re-sweep q; rs[row] += exp2(s)*wcol; per-row shuffle reduce;
//          one atomicAdd per (block,row) with bias/32 folded in.
// ---------------------------------------------------------------------------
__global__ __launch_bounds__(512) void k_attn(
    const ushort* __restrict__ Qb, const ushort* __restrict__ Kb,
    const float* __restrict__ vf, const float* __restrict__ bfp,
    float* __restrict__ outp)
{
    const int b    = blockIdx.y;
    const int k0   = blockIdx.x * 64;
    const int tid  = threadIdx.x;
    const int wave = tid >> 6;
    const int lane = tid & 63;
    const int quad = lane >> 4;
    const int col  = lane & 15;

    __shared__ float sl[8][64];
    __shared__ float wcol[64];

    // resident K fragments: 4 tiles x 2 chunks
    bf16x8 kf[4][2];
    {
        const ushort* Kbase = Kb + ((size_t)(b * SEQ + k0)) * DIM;
        #pragma unroll
        for (int t = 0; t < 4; ++t)
            #pragma unroll
            for (int c = 0; c < 2; ++c)
                kf[t][c] = *(const bf16x8*)(Kbase + (size_t)(t * 16 + col) * DIM + quad * 8 + c * 32);
    }

    const ushort* Qstart = Qb + ((size_t)(b * SEQ + wave * 256 + col)) * DIM + quad * 8;

    // ---- Phase A: column sums ----
    float l[4] = {0.f, 0.f, 0.f, 0.f};
    {
        const ushort* Qrow = Qstart;
        for (int qi = 0; qi < 16; ++qi) {
            bf16x8 a0 = *(const bf16x8*)(Qrow);
            bf16x8 a1 = *(const bf16x8*)(Qrow + 32);
            Qrow += 16 * DIM;
            #pragma unroll
            for (int t = 0; t < 4; ++t) {
                f32x4 acc = {0.f, 0.f, 0.f, 0.f};
                acc = __builtin_amdgcn_mfma_f32_16x16x32_bf16(a0, kf[t][0], acc, 0, 0, 0);
                acc = __builtin_amdgcn_mfma_f32_16x16x32_bf16(a1, kf[t][1], acc, 0, 0, 0);
                l[t] += fast_exp2(acc.x) + fast_exp2(acc.y) +
                        fast_exp2(acc.z) + fast_exp2(acc.w);
            }
        }
    }
    #pragma unroll
    for (int t = 0; t < 4; ++t) {
        l[t] += __shfl_xor(l[t], 16);
        l[t] += __shfl_xor(l[t], 32);
    }
    if (quad == 0) {
        #pragma unroll
        for (int t = 0; t < 4; ++t) sl[wave][t * 16 + col] = l[t];
    }
    __syncthreads();
    if (tid < 64) {
        float ll = 0.f;
        #pragma unroll
        for (int w = 0; w < 8; ++w) ll += sl[w][tid];
        wcol[tid] = vf[(size_t)b * SEQ + k0 + tid] / ll;
    }
    __syncthreads();

    // ---- Phase B: weighted row sums -> atomic accumulate ----
    const float bias = bfp[0] * (1.0f / (SEQ / 64));   // each block adds bf/32
    float wreg[4];
    #pragma unroll
    for (int t = 0; t < 4; ++t) wreg[t] = wcol[t * 16 + col];

    {
        const ushort* Qrow = Qstart;
        float* outb = outp + (size_t)b * SEQ;
        for (int qi = 0; qi < 16; ++qi) {
            bf16x8 a0 = *(const bf16x8*)(Qrow);
            bf16x8 a1 = *(const bf16x8*)(Qrow + 32);
            Qrow += 16 * DIM;
            float rs[4] = {0.f, 0.f, 0.f, 0.f};
            #pragma unroll
            for (int t = 0; t < 4; ++t) {
                f32x4 acc = {0.f, 0.f, 0.f, 0.f};
                acc = __builtin_amdgcn_mfma_f32_16x16x32_bf16(a0, kf[t][0], acc, 0, 0, 0);
                acc = __builtin_amdgcn_mfma_f32_16x16x32_bf16(a1, kf[t][1], acc, 0, 0, 0);
                #pragma unroll
                for (int r = 0; r < 4; ++r)
                    rs[r] += fast_exp2(acc[r]) * wreg[t];
            }
            // reduce over the 16 k-cols (low 4 lane bits)
            #pragma unroll
            for (int r = 0; r < 4; ++r) {
                float v = rs[r];
                v += __shfl_xor(v, 1); v += __shfl_xor(v, 2);
                v += __shfl_xor(v, 4); v += __shfl_xor(v, 8);
                rs[r] = v;
            }
            if (col == 0) {
                const int qrow = wave * 256 + qi * 16 + quad * 4;
                #pragma unroll
                for (int r = 0; r < 4; ++r)
                    atomicAdd(&outb[qrow + r], rs[r] + bias);
            }
        }
    }
}

// ---------------------------------------------------------------------------
extern "C" void kernel_launch(void* const* d_in, const int* in_sizes, int n_in,
                              void* d_out, int out_size, void* d_ws, size_t ws_size,
                              hipStream_t stream) {
    (void)in_sizes; (void)n_in; (void)ws_size;
    const float* x  = (const float*)d_in[0];
    const float* Wq = (const float*)d_in[1];
    const float* Wk = (const float*)d_in[2];
    const float* Wv = (const float*)d_in[3];
    const float* Wf = (const float*)d_in[4];
    const float* bf = (const float*)d_in[5];
    float* outp = (float*)d_out;

    float*  wvf = (float*)d_ws;                                  // 256 floats
    float*  vf  = wvf + 256;                                     // B*S
    ushort* Wt  = (ushort*)(vf + (size_t)BATCH * SEQ);           // 128*128
    ushort* Qb  = Wt + 128 * 128;                                // B*S*D bf16
    ushort* Kb  = Qb + (size_t)BATCH * SEQ * DIM;                // B*S*D bf16

    hipMemsetAsync(d_out, 0, (size_t)out_size * sizeof(float), stream);
    k_prep<<<1, 256, 0, stream>>>(Wq, Wk, Wv, Wf, Wt, wvf);
    k_qkv<<<BATCH * SEQ / 64, 256, 0, stream>>>(x, Wt, wvf, Qb, Kb, vf);
    k_attn<<<dim3(SEQ / 64, BATCH), 512, 0, stream>>>(Qb, Kb, vf, bf, outp);
}